// Round 2
// baseline (542.184 us; speedup 1.0000x reference)
//
#include <hip/hip_runtime.h>
#include <hip/hip_bf16.h>

#define BQ 8
#define DIM 512
#define NN 2048
#define MM 2048
#define TN 128
#define TM 128
#define TD 32
#define QUARTERS 4
#define MQ (MM / QUARTERS)   // 512

// ws layout: [b][quarter][n][4] floats  = {l, o0, o1, o2}; 8*4*2048*4 floats = 1 MB

__global__ __launch_bounds__(256) void attn_corr_kernel(
    const float* __restrict__ src_emb,   // [B, D, N]
    const float* __restrict__ tgt_emb,   // [B, D, M]
    const float* __restrict__ tgt,       // [B, 3, M]
    float* __restrict__ ws)
{
    const int nt = blockIdx.x;           // 0..15  n tile
    const int qt = blockIdx.y;           // 0..3   m quarter
    const int b  = blockIdx.z;           // 0..7
    const int t  = threadIdx.x;          // 0..255
    const int tx = t & 15;               // m sub-index
    const int ty = t >> 4;               // n sub-index

    const int n0 = nt * TN;

    __shared__ float As[TD][TN];
    __shared__ float Bs[TD][TM];
    __shared__ float Vs[3][TM];

    const float* Ab = src_emb + (size_t)b * DIM * NN;
    const float* Bb = tgt_emb + (size_t)b * DIM * MM;
    const float* Tb = tgt     + (size_t)b * 3 * MM;

    float l_acc[8] = {0,0,0,0,0,0,0,0};
    float o_acc[3][8] = {};

    // exp(s/sqrt(512)) = exp2(s * (log2e/sqrt(512)))
    const float SCALE = 0.044194173824159216f * 1.4426950408889634f;

    for (int mt = 0; mt < MQ / TM; mt++) {     // 4 m-tiles
        const int m0 = qt * MQ + mt * TM;

        float acc[8][8] = {};

        for (int kt = 0; kt < DIM / TD; kt++) {    // 16 k-iters
            // stage A,B tiles: 32x128 floats each, 4 float4 per thread per matrix
            #pragma unroll
            for (int i = 0; i < 4; i++) {
                int idx = t * 4 + i * 1024;
                int d = idx >> 7;          // 0..31
                int n = idx & 127;
                *(float4*)&As[d][n] = *(const float4*)&Ab[(size_t)(kt * TD + d) * NN + n0 + n];
                *(float4*)&Bs[d][n] = *(const float4*)&Bb[(size_t)(kt * TD + d) * MM + m0 + n];
            }
            __syncthreads();

            #pragma unroll 4
            for (int k = 0; k < TD; k++) {
                float a[8], bv[8];
                *(float4*)&a[0]  = *(const float4*)&As[k][ty * 8];
                *(float4*)&a[4]  = *(const float4*)&As[k][ty * 8 + 4];
                *(float4*)&bv[0] = *(const float4*)&Bs[k][tx * 8];
                *(float4*)&bv[4] = *(const float4*)&Bs[k][tx * 8 + 4];
                #pragma unroll
                for (int i = 0; i < 8; i++)
                    #pragma unroll
                    for (int j = 0; j < 8; j++)
                        acc[i][j] += a[i] * bv[j];
            }
            __syncthreads();
        }

        // stage V (tgt) rows for this m tile: 3 x 128 floats
        if (t < 96) {
            int idx = t * 4;
            int r = idx >> 7;
            int c = idx & 127;
            *(float4*)&Vs[r][c] = *(const float4*)&Tb[(size_t)r * MM + m0 + c];
        }
        __syncthreads();

        #pragma unroll
        for (int j = 0; j < 8; j++) {
            float v0 = Vs[0][tx * 8 + j];
            float v1 = Vs[1][tx * 8 + j];
            float v2 = Vs[2][tx * 8 + j];
            #pragma unroll
            for (int i = 0; i < 8; i++) {
                float e = __builtin_amdgcn_exp2f(acc[i][j] * SCALE);
                l_acc[i]    += e;
                o_acc[0][i] += e * v0;
                o_acc[1][i] += e * v1;
                o_acc[2][i] += e * v2;
            }
        }
        __syncthreads();
    }

    // reduce across tx (16 lanes sharing same n rows; contiguous lane groups)
    #pragma unroll
    for (int m = 1; m <= 8; m <<= 1) {
        #pragma unroll
        for (int i = 0; i < 8; i++) {
            l_acc[i]    += __shfl_xor(l_acc[i], m);
            o_acc[0][i] += __shfl_xor(o_acc[0][i], m);
            o_acc[1][i] += __shfl_xor(o_acc[1][i], m);
            o_acc[2][i] += __shfl_xor(o_acc[2][i], m);
        }
    }

    if (tx == 0) {
        #pragma unroll
        for (int i = 0; i < 8; i++) {
            int n = n0 + ty * 8 + i;
            float4 v = make_float4(l_acc[i], o_acc[0][i], o_acc[1][i], o_acc[2][i]);
            ((float4*)ws)[((size_t)(b * QUARTERS + qt) * NN) + n] = v;
        }
    }
}

__global__ __launch_bounds__(256) void head_kernel(
    const float* __restrict__ ws,
    const float* __restrict__ src,       // [B,3,N]
    const float* __restrict__ tgt,       // [B,3,M]
    float* __restrict__ out)             // [72 R][24 t]
{
    const int b = blockIdx.x;
    const int t = threadIdx.x;

    float pp[3][3] = {};
    float sc[3] = {0,0,0};
    float ss[3] = {0,0,0};
    float st[3] = {0,0,0};

    const float4* w4 = (const float4*)ws;
    const float* S = src + (size_t)b * 3 * NN;
    const float* T = tgt + (size_t)b * 3 * MM;

    for (int n = t; n < NN; n += 256) {
        float4 q0 = w4[(size_t)(b * QUARTERS + 0) * NN + n];
        float4 q1 = w4[(size_t)(b * QUARTERS + 1) * NN + n];
        float4 q2 = w4[(size_t)(b * QUARTERS + 2) * NN + n];
        float4 q3 = w4[(size_t)(b * QUARTERS + 3) * NN + n];
        float l  = q0.x + q1.x + q2.x + q3.x;
        float inv = 1.0f / l;
        float c0 = (q0.y + q1.y + q2.y + q3.y) * inv;
        float c1 = (q0.z + q1.z + q2.z + q3.z) * inv;
        float c2 = (q0.w + q1.w + q2.w + q3.w) * inv;
        float s0 = S[n], s1 = S[NN + n], s2 = S[2 * NN + n];
        sc[0] += c0; sc[1] += c1; sc[2] += c2;
        ss[0] += s0; ss[1] += s1; ss[2] += s2;
        st[0] += T[n]; st[1] += T[MM + n]; st[2] += T[2 * MM + n];
        pp[0][0] += s0 * c0; pp[0][1] += s0 * c1; pp[0][2] += s0 * c2;
        pp[1][0] += s1 * c0; pp[1][1] += s1 * c1; pp[1][2] += s1 * c2;
        pp[2][0] += s2 * c0; pp[2][1] += s2 * c1; pp[2][2] += s2 * c2;
    }

    __shared__ float red[256];
    __shared__ float res[18];
    float vals[18];
    vals[0] = ss[0]; vals[1] = ss[1]; vals[2] = ss[2];
    vals[3] = sc[0]; vals[4] = sc[1]; vals[5] = sc[2];
    vals[6] = st[0]; vals[7] = st[1]; vals[8] = st[2];
    vals[9]  = pp[0][0]; vals[10] = pp[0][1]; vals[11] = pp[0][2];
    vals[12] = pp[1][0]; vals[13] = pp[1][1]; vals[14] = pp[1][2];
    vals[15] = pp[2][0]; vals[16] = pp[2][1]; vals[17] = pp[2][2];

    for (int c = 0; c < 18; c++) {
        red[t] = vals[c];
        __syncthreads();
        for (int off = 128; off > 0; off >>= 1) {
            if (t < off) red[t] += red[t + off];
            __syncthreads();
        }
        if (t == 0) res[c] = red[0];
        __syncthreads();
    }

    if (t == 0) {
        const float invN = 1.0f / (float)NN;
        float mus[3], muc[3], mut[3], H[3][3];
        for (int i = 0; i < 3; i++) {
            mus[i] = res[i] * invN;
            muc[i] = res[3 + i] * invN;
            mut[i] = res[6 + i] * invN;
        }
        for (int i = 0; i < 3; i++)
            for (int j = 0; j < 3; j++)
                H[i][j] = res[9 + i * 3 + j] - (float)NN * mus[i] * muc[j];

        // A = H^T H
        float A[3][3];
        for (int i = 0; i < 3; i++)
            for (int j = 0; j < 3; j++)
                A[i][j] = H[0][i] * H[0][j] + H[1][i] * H[1][j] + H[2][i] * H[2][j];

        float V[3][3] = {{1,0,0},{0,1,0},{0,0,1}};
        for (int sweep = 0; sweep < 10; sweep++) {
            for (int pi = 0; pi < 3; pi++) {
                int p = (pi < 2) ? 0 : 1;
                int q = (pi == 0) ? 1 : 2;
                float apq = A[p][q];
                if (fabsf(apq) < 1e-30f) continue;
                float tau = (A[q][q] - A[p][p]) / (2.0f * apq);
                float tt = (tau >= 0.0f) ? 1.0f / (tau + sqrtf(1.0f + tau * tau))
                                         : -1.0f / (-tau + sqrtf(1.0f + tau * tau));
                float c = 1.0f / sqrtf(1.0f + tt * tt);
                float s = tt * c;
                for (int k = 0; k < 3; k++) {          // A <- A G
                    float akp = A[k][p], akq = A[k][q];
                    A[k][p] = c * akp - s * akq;
                    A[k][q] = s * akp + c * akq;
                }
                for (int k = 0; k < 3; k++) {          // A <- G^T A
                    float apk = A[p][k], aqk = A[q][k];
                    A[p][k] = c * apk - s * aqk;
                    A[q][k] = s * apk + c * aqk;
                }
                for (int k = 0; k < 3; k++) {          // V <- V G
                    float vkp = V[k][p], vkq = V[k][q];
                    V[k][p] = c * vkp - s * vkq;
                    V[k][q] = s * vkp + c * vkq;
                }
            }
        }

        // sort eigenpairs descending
        float lam[3] = {A[0][0], A[1][1], A[2][2]};
        int idx[3] = {0, 1, 2};
        for (int a = 0; a < 2; a++)
            for (int bb = 0; bb < 2 - a; bb++)
                if (lam[idx[bb]] < lam[idx[bb + 1]]) { int tmp = idx[bb]; idx[bb] = idx[bb + 1]; idx[bb + 1] = tmp; }

        float Vc[3][3], U[3][3];
        for (int c = 0; c < 3; c++) {
            float sv = sqrtf(fmaxf(lam[idx[c]], 0.0f));
            float isv = 1.0f / fmaxf(sv, 1e-20f);
            for (int r = 0; r < 3; r++) {
                Vc[r][c] = V[r][idx[c]];
                U[r][c] = (H[r][0] * V[0][idx[c]] + H[r][1] * V[1][idx[c]] + H[r][2] * V[2][idx[c]]) * isv;
            }
        }

        // Gram-Schmidt cleanup of U columns
        {
            float nrm = rsqrtf(U[0][0]*U[0][0] + U[1][0]*U[1][0] + U[2][0]*U[2][0]);
            for (int r = 0; r < 3; r++) U[r][0] *= nrm;
            float d01 = U[0][0]*U[0][1] + U[1][0]*U[1][1] + U[2][0]*U[2][1];
            for (int r = 0; r < 3; r++) U[r][1] -= d01 * U[r][0];
            nrm = rsqrtf(U[0][1]*U[0][1] + U[1][1]*U[1][1] + U[2][1]*U[2][1]);
            for (int r = 0; r < 3; r++) U[r][1] *= nrm;
            float d02 = U[0][0]*U[0][2] + U[1][0]*U[1][2] + U[2][0]*U[2][2];
            float d12 = U[0][1]*U[0][2] + U[1][1]*U[1][2] + U[2][1]*U[2][2];
            for (int r = 0; r < 3; r++) U[r][2] -= d02 * U[r][0] + d12 * U[r][1];
            nrm = rsqrtf(U[0][2]*U[0][2] + U[1][2]*U[1][2] + U[2][2]*U[2][2]);
            for (int r = 0; r < 3; r++) U[r][2] *= nrm;
        }

        float det = H[0][0]*(H[1][1]*H[2][2] - H[1][2]*H[2][1])
                  - H[0][1]*(H[1][0]*H[2][2] - H[1][2]*H[2][0])
                  + H[0][2]*(H[1][0]*H[2][1] - H[1][1]*H[2][0]);
        float sgn = (det < 0.0f) ? -1.0f : 1.0f;

        float R[3][3];
        for (int i = 0; i < 3; i++)
            for (int j = 0; j < 3; j++)
                R[i][j] = Vc[i][0]*U[j][0] + Vc[i][1]*U[j][1] + sgn * Vc[i][2]*U[j][2];

        for (int i = 0; i < 3; i++)
            for (int j = 0; j < 3; j++)
                out[b * 9 + i * 3 + j] = R[i][j];
        for (int i = 0; i < 3; i++)
            out[BQ * 9 + b * 3 + i] = mut[i] - (R[i][0]*mus[0] + R[i][1]*mus[1] + R[i][2]*mus[2]);
    }
}

extern "C" void kernel_launch(void* const* d_in, const int* in_sizes, int n_in,
                              void* d_out, int out_size, void* d_ws, size_t ws_size,
                              hipStream_t stream) {
    const float* src_emb = (const float*)d_in[0];
    const float* tgt_emb = (const float*)d_in[1];
    const float* src     = (const float*)d_in[2];
    const float* tgt     = (const float*)d_in[3];
    float* out = (float*)d_out;
    float* ws  = (float*)d_ws;

    dim3 grid1(NN / TN, QUARTERS, BQ);   // 16 x 4 x 8 = 512 blocks
    attn_corr_kernel<<<grid1, 256, 0, stream>>>(src_emb, tgt_emb, tgt, ws);
    head_kernel<<<BQ, 256, 0, stream>>>(ws, src, tgt, out);
}

// Round 4
// 180.600 us; speedup vs baseline: 3.0021x; 3.0021x over previous
//
#include <hip/hip_runtime.h>
#include <hip/hip_bf16.h>

#define BQ 8
#define DIM 512
#define NN 2048
#define MM 2048
#define QUARTERS 4

typedef __attribute__((ext_vector_type(8))) short short8;
typedef __attribute__((ext_vector_type(4))) float floatx4;

// ws layout:
//   [0, 2MiB)        : partials [b][qt*2 + mhalf][n] float4 {l, o0, o1, o2}
//   [2MiB, 18MiB)    : Abf  [B][N][D] bf16  (transposed src_embedding)
//   [18MiB, 34MiB)   : Bbf  [B][M][D] bf16  (transposed tgt_embedding)

// ---------------- transpose + fp32->bf16 cast ----------------
__global__ __launch_bounds__(256) void transpose_cast_kernel(
    const float* __restrict__ src_emb,   // [B, D, N]
    const float* __restrict__ tgt_emb,   // [B, D, M]
    __hip_bfloat16* __restrict__ Abf,    // [B, N, D]
    __hip_bfloat16* __restrict__ Bbf)    // [B, M, D]
{
    const int n0 = blockIdx.x * 64;
    const int d0 = blockIdx.y * 64;
    const int b  = blockIdx.z & 7;
    const int which = blockIdx.z >> 3;

    const float* in = (which == 0 ? src_emb : tgt_emb) + (size_t)b * DIM * NN;
    __hip_bfloat16* out = (which == 0 ? Abf : Bbf) + (size_t)b * NN * DIM;

    __shared__ float tl[64][65];

    const int t = threadIdx.x;
    const int u = t & 15;         // 16 column groups of 4
    const int r = t >> 4;         // 16 rows

    #pragma unroll
    for (int rr = r; rr < 64; rr += 16) {
        float4 v = *(const float4*)&in[(size_t)(d0 + rr) * NN + n0 + u * 4];
        tl[rr][u * 4 + 0] = v.x;
        tl[rr][u * 4 + 1] = v.y;
        tl[rr][u * 4 + 2] = v.z;
        tl[rr][u * 4 + 3] = v.w;
    }
    __syncthreads();

    #pragma unroll
    for (int rn = r; rn < 64; rn += 16) {
        ushort4 o;
        __hip_bfloat16 h0 = __float2bfloat16(tl[u * 4 + 0][rn]);
        __hip_bfloat16 h1 = __float2bfloat16(tl[u * 4 + 1][rn]);
        __hip_bfloat16 h2 = __float2bfloat16(tl[u * 4 + 2][rn]);
        __hip_bfloat16 h3 = __float2bfloat16(tl[u * 4 + 3][rn]);
        o.x = *(unsigned short*)&h0;
        o.y = *(unsigned short*)&h1;
        o.z = *(unsigned short*)&h2;
        o.w = *(unsigned short*)&h3;
        *(ushort4*)&out[(size_t)(n0 + rn) * DIM + d0 + u * 4] = o;
    }
}

// ---------------- MFMA attention + soft correspondence ----------------
// grid (16 n-tiles, 4 m-quarters, 8 b), 256 threads (4 waves, each 64x64).
// Wave w covers n-half (w>>1), m-half (w&1). Each wave writes its OWN partial
// slot [b][qt*2 + (w&1)][n] — waves sharing an n-half must NOT share slots
// (R3 bug: last-writer-wins race lost half the softmax sum).
#define LROW 72   // LDS row stride in shorts (64 data + 8 pad)

__global__ __launch_bounds__(256, 2) void attn_mfma_kernel(
    const __hip_bfloat16* __restrict__ Abf,  // [B, N, D]
    const __hip_bfloat16* __restrict__ Bbf,  // [B, M, D]
    const float* __restrict__ tgt,           // [B, 3, M]
    float* __restrict__ part)                // [b][qt*2+mh][n] float4
{
    const int nt = blockIdx.x;      // 0..15
    const int qt = blockIdx.y;      // 0..3
    const int b  = blockIdx.z;      // 0..7
    const int t  = threadIdx.x;
    const int wave = t >> 6;
    const int lane = t & 63;
    const int lm   = lane & 15;
    const int quad = lane >> 4;
    const int wn = (wave >> 1) * 64;   // wave's n offset in 128 tile
    const int wm = (wave & 1) * 64;    // wave's m offset in 128 tile

    __shared__ short As[128 * LROW];
    __shared__ short Bs[128 * LROW];
    __shared__ float Vs[3][128];

    const __hip_bfloat16* Abase = Abf + ((size_t)(b * NN + nt * 128)) * DIM;
    const float* Tb = tgt + (size_t)b * 3 * MM;

    const float SCALE = 0.044194173824159216f * 1.4426950408889634f;

    float l_acc[4][4] = {};
    float o0a[4][4] = {}, o1a[4][4] = {}, o2a[4][4] = {};

    for (int mt = 0; mt < 4; mt++) {
        const int m0 = qt * 512 + mt * 128;
        const __hip_bfloat16* Bbase = Bbf + ((size_t)(b * MM + m0)) * DIM;

        floatx4 acc[4][4];
        #pragma unroll
        for (int i = 0; i < 4; i++)
            #pragma unroll
            for (int j = 0; j < 4; j++)
                acc[i][j] = (floatx4){0.f, 0.f, 0.f, 0.f};

        for (int kt = 0; kt < 8; kt++) {     // d chunks of 64
            const int k0 = kt * 64;
            #pragma unroll
            for (int i = 0; i < 4; i++) {
                int idx = i * 256 + t;
                int row = idx >> 3;          // 0..127
                int c16 = idx & 7;           // 16B chunk within row
                *(uint4*)&As[row * LROW + c16 * 8] =
                    *(const uint4*)&Abase[(size_t)row * DIM + k0 + c16 * 8];
                *(uint4*)&Bs[row * LROW + c16 * 8] =
                    *(const uint4*)&Bbase[(size_t)row * DIM + k0 + c16 * 8];
            }
            __syncthreads();

            #pragma unroll
            for (int ks = 0; ks < 2; ks++) {
                short8 af[4], bf[4];
                #pragma unroll
                for (int i = 0; i < 4; i++)
                    af[i] = *(const short8*)&As[(wn + i * 16 + lm) * LROW + ks * 32 + quad * 8];
                #pragma unroll
                for (int j = 0; j < 4; j++)
                    bf[j] = *(const short8*)&Bs[(wm + j * 16 + lm) * LROW + ks * 32 + quad * 8];
                #pragma unroll
                for (int i = 0; i < 4; i++)
                    #pragma unroll
                    for (int j = 0; j < 4; j++)
                        acc[i][j] = __builtin_amdgcn_mfma_f32_16x16x32_bf16(af[i], bf[j], acc[i][j], 0, 0, 0);
            }
            __syncthreads();
        }

        // stage V rows (fp32) for this m tile
        if (t < 96) {
            int r = t >> 5;
            int c = (t & 31) * 4;
            *(float4*)&Vs[r][c] = *(const float4*)&Tb[(size_t)r * MM + m0 + c];
        }
        __syncthreads();

        // C/D layout (m89/m91): col = lane&15 (B side / m), row = quad*4+reg (A side / n)
        #pragma unroll
        for (int j = 0; j < 4; j++) {
            int vcol = wm + j * 16 + lm;
            float v0 = Vs[0][vcol];
            float v1 = Vs[1][vcol];
            float v2 = Vs[2][vcol];
            #pragma unroll
            for (int i = 0; i < 4; i++) {
                #pragma unroll
                for (int r = 0; r < 4; r++) {
                    float e = __builtin_amdgcn_exp2f(acc[i][j][r] * SCALE);
                    l_acc[i][r] += e;
                    o0a[i][r] += e * v0;
                    o1a[i][r] += e * v1;
                    o2a[i][r] += e * v2;
                }
            }
        }
        __syncthreads();
    }

    // reduce across the 16 lm lanes of each quad group (sums over this wave's m-half)
    #pragma unroll
    for (int m = 1; m <= 8; m <<= 1) {
        #pragma unroll
        for (int i = 0; i < 4; i++)
            #pragma unroll
            for (int r = 0; r < 4; r++) {
                l_acc[i][r] += __shfl_xor(l_acc[i][r], m);
                o0a[i][r]  += __shfl_xor(o0a[i][r], m);
                o1a[i][r]  += __shfl_xor(o1a[i][r], m);
                o2a[i][r]  += __shfl_xor(o2a[i][r], m);
            }
    }

    if (lm == 0) {
        const size_t slot = (size_t)((b * QUARTERS + qt) * 2 + (wave & 1)) * NN;
        #pragma unroll
        for (int i = 0; i < 4; i++)
            #pragma unroll
            for (int r = 0; r < 4; r++) {
                int n = nt * 128 + wn + i * 16 + quad * 4 + r;
                ((float4*)part)[slot + n] =
                    make_float4(l_acc[i][r], o0a[i][r], o1a[i][r], o2a[i][r]);
            }
    }
}

// ---------------- head: combine partials, Procrustes ----------------
__global__ __launch_bounds__(256) void head_kernel(
    const float* __restrict__ ws,
    const float* __restrict__ src,       // [B,3,N]
    const float* __restrict__ tgt,       // [B,3,M]
    float* __restrict__ out)             // [72 R][24 t]
{
    const int b = blockIdx.x;
    const int t = threadIdx.x;

    float pp[3][3] = {};
    float sc[3] = {0,0,0};
    float ss[3] = {0,0,0};
    float st[3] = {0,0,0};

    const float4* w4 = (const float4*)ws;
    const float* S = src + (size_t)b * 3 * NN;
    const float* T = tgt + (size_t)b * 3 * MM;

    for (int n = t; n < NN; n += 256) {
        float l = 0.f, y0 = 0.f, y1 = 0.f, y2 = 0.f;
        #pragma unroll
        for (int q = 0; q < 8; q++) {
            float4 p = w4[(size_t)(b * 8 + q) * NN + n];
            l += p.x; y0 += p.y; y1 += p.z; y2 += p.w;
        }
        float inv = 1.0f / l;
        float c0 = y0 * inv;
        float c1 = y1 * inv;
        float c2 = y2 * inv;
        float s0 = S[n], s1 = S[NN + n], s2 = S[2 * NN + n];
        sc[0] += c0; sc[1] += c1; sc[2] += c2;
        ss[0] += s0; ss[1] += s1; ss[2] += s2;
        st[0] += T[n]; st[1] += T[MM + n]; st[2] += T[2 * MM + n];
        pp[0][0] += s0 * c0; pp[0][1] += s0 * c1; pp[0][2] += s0 * c2;
        pp[1][0] += s1 * c0; pp[1][1] += s1 * c1; pp[1][2] += s1 * c2;
        pp[2][0] += s2 * c0; pp[2][1] += s2 * c1; pp[2][2] += s2 * c2;
    }

    float vals[18];
    vals[0] = ss[0]; vals[1] = ss[1]; vals[2] = ss[2];
    vals[3] = sc[0]; vals[4] = sc[1]; vals[5] = sc[2];
    vals[6] = st[0]; vals[7] = st[1]; vals[8] = st[2];
    vals[9]  = pp[0][0]; vals[10] = pp[0][1]; vals[11] = pp[0][2];
    vals[12] = pp[1][0]; vals[13] = pp[1][1]; vals[14] = pp[1][2];
    vals[15] = pp[2][0]; vals[16] = pp[2][1]; vals[17] = pp[2][2];

    // wave-level reduction (64 lanes), then combine 4 waves via LDS
    #pragma unroll
    for (int m = 1; m <= 32; m <<= 1)
        #pragma unroll
        for (int c = 0; c < 18; c++)
            vals[c] += __shfl_xor(vals[c], m);

    __shared__ float warr[4][18];
    const int wave = t >> 6;
    if ((t & 63) == 0)
        #pragma unroll
        for (int c = 0; c < 18; c++) warr[wave][c] = vals[c];
    __syncthreads();

    if (t == 0) {
        float res[18];
        #pragma unroll
        for (int c = 0; c < 18; c++)
            res[c] = warr[0][c] + warr[1][c] + warr[2][c] + warr[3][c];

        const float invN = 1.0f / (float)NN;
        float mus[3], muc[3], mut[3], H[3][3];
        for (int i = 0; i < 3; i++) {
            mus[i] = res[i] * invN;
            muc[i] = res[3 + i] * invN;
            mut[i] = res[6 + i] * invN;
        }
        for (int i = 0; i < 3; i++)
            for (int j = 0; j < 3; j++)
                H[i][j] = res[9 + i * 3 + j] - (float)NN * mus[i] * muc[j];

        // A = H^T H
        float A[3][3];
        for (int i = 0; i < 3; i++)
            for (int j = 0; j < 3; j++)
                A[i][j] = H[0][i] * H[0][j] + H[1][i] * H[1][j] + H[2][i] * H[2][j];

        float V[3][3] = {{1,0,0},{0,1,0},{0,0,1}};
        for (int sweep = 0; sweep < 6; sweep++) {
            for (int pi = 0; pi < 3; pi++) {
                int p = (pi < 2) ? 0 : 1;
                int q = (pi == 0) ? 1 : 2;
                float apq = A[p][q];
                if (fabsf(apq) < 1e-30f) continue;
                float tau = (A[q][q] - A[p][p]) / (2.0f * apq);
                float tt = (tau >= 0.0f) ? 1.0f / (tau + sqrtf(1.0f + tau * tau))
                                         : -1.0f / (-tau + sqrtf(1.0f + tau * tau));
                float c = 1.0f / sqrtf(1.0f + tt * tt);
                float s = tt * c;
                for (int k = 0; k < 3; k++) {
                    float akp = A[k][p], akq = A[k][q];
                    A[k][p] = c * akp - s * akq;
                    A[k][q] = s * akp + c * akq;
                }
                for (int k = 0; k < 3; k++) {
                    float apk = A[p][k], aqk = A[q][k];
                    A[p][k] = c * apk - s * aqk;
                    A[q][k] = s * apk + c * aqk;
                }
                for (int k = 0; k < 3; k++) {
                    float vkp = V[k][p], vkq = V[k][q];
                    V[k][p] = c * vkp - s * vkq;
                    V[k][q] = s * vkp + c * vkq;
                }
            }
        }

        float lam[3] = {A[0][0], A[1][1], A[2][2]};
        int idx[3] = {0, 1, 2};
        for (int a = 0; a < 2; a++)
            for (int bb = 0; bb < 2 - a; bb++)
                if (lam[idx[bb]] < lam[idx[bb + 1]]) { int tmp = idx[bb]; idx[bb] = idx[bb + 1]; idx[bb + 1] = tmp; }

        float Vc[3][3], U[3][3];
        for (int c = 0; c < 3; c++) {
            float sv = sqrtf(fmaxf(lam[idx[c]], 0.0f));
            float isv = 1.0f / fmaxf(sv, 1e-20f);
            for (int r = 0; r < 3; r++) {
                Vc[r][c] = V[r][idx[c]];
                U[r][c] = (H[r][0] * V[0][idx[c]] + H[r][1] * V[1][idx[c]] + H[r][2] * V[2][idx[c]]) * isv;
            }
        }

        // Gram-Schmidt cleanup of U columns
        {
            float nrm = rsqrtf(U[0][0]*U[0][0] + U[1][0]*U[1][0] + U[2][0]*U[2][0]);
            for (int r = 0; r < 3; r++) U[r][0] *= nrm;
            float d01 = U[0][0]*U[0][1] + U[1][0]*U[1][1] + U[2][0]*U[2][1];
            for (int r = 0; r < 3; r++) U[r][1] -= d01 * U[r][0];
            nrm = rsqrtf(U[0][1]*U[0][1] + U[1][1]*U[1][1] + U[2][1]*U[2][1]);
            for (int r = 0; r < 3; r++) U[r][1] *= nrm;
            float d02 = U[0][0]*U[0][2] + U[1][0]*U[1][2] + U[2][0]*U[2][2];
            float d12 = U[0][1]*U[0][2] + U[1][1]*U[1][2] + U[2][1]*U[2][2];
            for (int r = 0; r < 3; r++) U[r][2] -= d02 * U[r][0] + d12 * U[r][1];
            nrm = rsqrtf(U[0][2]*U[0][2] + U[1][2]*U[1][2] + U[2][2]*U[2][2]);
            for (int r = 0; r < 3; r++) U[r][2] *= nrm;
        }

        float det = H[0][0]*(H[1][1]*H[2][2] - H[1][2]*H[2][1])
                  - H[0][1]*(H[1][0]*H[2][2] - H[1][2]*H[2][0])
                  + H[0][2]*(H[1][0]*H[2][1] - H[1][1]*H[2][0]);
        float sgn = (det < 0.0f) ? -1.0f : 1.0f;

        float R[3][3];
        for (int i = 0; i < 3; i++)
            for (int j = 0; j < 3; j++)
                R[i][j] = Vc[i][0]*U[j][0] + Vc[i][1]*U[j][1] + sgn * Vc[i][2]*U[j][2];

        for (int i = 0; i < 3; i++)
            for (int j = 0; j < 3; j++)
                out[b * 9 + i * 3 + j] = R[i][j];
        for (int i = 0; i < 3; i++)
            out[BQ * 9 + b * 3 + i] = mut[i] - (R[i][0]*mus[0] + R[i][1]*mus[1] + R[i][2]*mus[2]);
    }
}

extern "C" void kernel_launch(void* const* d_in, const int* in_sizes, int n_in,
                              void* d_out, int out_size, void* d_ws, size_t ws_size,
                              hipStream_t stream) {
    const float* src_emb = (const float*)d_in[0];
    const float* tgt_emb = (const float*)d_in[1];
    const float* src     = (const float*)d_in[2];
    const float* tgt     = (const float*)d_in[3];
    float* out = (float*)d_out;

    float* part = (float*)d_ws;                                            // 2 MiB
    __hip_bfloat16* Abf = (__hip_bfloat16*)((char*)d_ws + (2 << 20));       // 16 MiB
    __hip_bfloat16* Bbf = (__hip_bfloat16*)((char*)d_ws + (18 << 20));      // 16 MiB

    dim3 gridT(NN / 64, DIM / 64, 2 * BQ);    // 32 x 8 x 16 = 4096 blocks
    transpose_cast_kernel<<<gridT, 256, 0, stream>>>(src_emb, tgt_emb, Abf, Bbf);

    dim3 gridA(NN / 128, QUARTERS, BQ);       // 16 x 4 x 8 = 512 blocks
    attn_mfma_kernel<<<gridA, 256, 0, stream>>>(Abf, Bbf, tgt, part);

    head_kernel<<<BQ, 256, 0, stream>>>(part, src, tgt, out);
}